// Round 1
// baseline (173.043 us; speedup 1.0000x reference)
//
#include <hip/hip_runtime.h>

#define BB   128
#define TT   512
#define FF   40
#define WW   10
#define NS   503          // number of window starts (stride 1, T-W+1)
#define NP   780          // F*(F-1)/2 upper-triangle pairs
#define EPSC 1e-5f

// One block per (b, s). Window rows s..s+W-1 are contiguous in memory:
// 400 consecutive floats -> coalesced LDS stage.
__global__ __launch_bounds__(256) void ts_corr_kernel(const float* __restrict__ in,
                                                      float* __restrict__ out) {
    const int bs  = blockIdx.x;          // b*NS + s
    const int b   = bs / NS;
    const int s   = bs - b * NS;
    const int tid = threadIdx.x;

    __shared__ float xs[WW * FF];        // 400 floats, window slab
    __shared__ float mean_s[FF];
    __shared__ float istd_s[FF];

    const float* src = in + (size_t)b * (TT * FF) + (size_t)s * FF;
    for (int i = tid; i < WW * FF; i += 256) xs[i] = src[i];
    __syncthreads();

    if (tid < FF) {
        float sum = 0.f;
        #pragma unroll
        for (int w = 0; w < WW; ++w) sum += xs[w * FF + tid];
        const float m = sum * (1.0f / WW);
        float v = 0.f;
        #pragma unroll
        for (int w = 0; w < WW; ++w) { float d = xs[w * FF + tid] - m; v += d * d; }
        v *= (1.0f / WW);
        mean_s[tid] = m;
        istd_s[tid] = 1.0f / (sqrtf(v) + EPSC);   // matches ref: cov/((sqrt(v)+eps)*(...))
    }
    __syncthreads();

    float* dst = out + (size_t)bs * NP;
    for (int p = tid; p < NP; p += 256) {
        // unrank p -> (i, j), i<j, row-major triu ordering.
        // offset(i) = i*(2F-1-i)/2 = i*(79-i)/2 for F=40
        int i = (int)((79.0f - sqrtf((float)(6241 - 8 * p))) * 0.5f);
        while (i > 0 && i * (79 - i) / 2 > p) --i;
        while ((i + 1) * (79 - (i + 1)) / 2 <= p) ++i;
        const int j = p - i * (79 - i) / 2 + i + 1;

        float dot = 0.f;
        #pragma unroll
        for (int w = 0; w < WW; ++w) dot += xs[w * FF + i] * xs[w * FF + j];
        const float c = (dot * (1.0f / WW) - mean_s[i] * mean_s[j]) * istd_s[i] * istd_s[j];
        dst[p] = c;
    }
}

extern "C" void kernel_launch(void* const* d_in, const int* in_sizes, int n_in,
                              void* d_out, int out_size, void* d_ws, size_t ws_size,
                              hipStream_t stream) {
    const float* in = (const float*)d_in[0];
    float* out = (float*)d_out;
    const int grid = BB * NS;   // 64384 blocks
    ts_corr_kernel<<<grid, 256, 0, stream>>>(in, out);
}

// Round 3
// 100.071 us; speedup vs baseline: 1.7292x; 1.7292x over previous
//
#include <hip/hip_runtime.h>

#define BB   128
#define TT   512
#define FF   40
#define WW   10
#define NS   503            // window starts (stride 1): T-W+1
#define NP   780            // F*(F-1)/2
#define SC   64             // s-steps per block
#define NCHUNK 8            // ceil(NS/SC)
#define NSLOT 4             // 256*4 = 1024 >= 780 pair slots
#define EPSC 1e-5f

// One block per (b, s-chunk). Rolling window sums:
//   per-thread: up to 4 pairs, register Sxy updated with +new*new - old*old
//   lanes 0..39: rolling Sx/Sxx -> (mean, istd) float2 table, double-buffered
__global__ __launch_bounds__(256) void ts_corr_roll(const float* __restrict__ in,
                                                    float* __restrict__ out) {
    const int blk = blockIdx.x;
    const int b   = blk / NCHUNK;
    const int c   = blk - b * NCHUNK;
    const int s0  = c * SC;
    const int steps = min(SC, NS - s0);        // last chunk: 55
    const int rows  = steps + WW - 1;          // <= 73
    const int tid = threadIdx.x;

    __shared__ float  xs[SC + WW - 1][FF];     // 73*40 floats = 11.7 KB
    __shared__ float2 stats[2][FF];            // (mean, istd), double-buffered

    // Stage rows [s0, s0+rows): one contiguous slab, float4-vectorized.
    const float*  src  = in + ((size_t)b * TT + s0) * FF;
    const float4* src4 = (const float4*)src;
    float4*       xs4  = (float4*)&xs[0][0];
    const int nv4 = rows * FF / 4;             // FF%4==0
    for (int i = tid; i < nv4; i += 256) xs4[i] = src4[i];
    __syncthreads();

    // Pair slots: p = tid + k*256, coalesced writes.
    int  pi[NSLOT], pj[NSLOT];
    bool act[NSLOT];
    float sxy[NSLOT];
    #pragma unroll
    for (int k = 0; k < NSLOT; ++k) {
        const int p = tid + k * 256;
        act[k] = (p < NP);
        const int pp = act[k] ? p : 0;
        int i = (int)((79.0f - sqrtf((float)(6241 - 8 * pp))) * 0.5f);
        while (i > 0 && i * (79 - i) / 2 > pp) --i;
        while ((i + 1) * (79 - (i + 1)) / 2 <= pp) ++i;
        pi[k] = i;
        pj[k] = pp - i * (79 - i) / 2 + i + 1;
        float s = 0.f;
        #pragma unroll
        for (int w = 0; w < WW; ++w) s += xs[w][pi[k]] * xs[w][pj[k]];
        sxy[k] = s;
    }

    // Per-feature rolling sums (lanes 0..39).
    float sx = 0.f, sxx = 0.f;
    if (tid < FF) {
        #pragma unroll
        for (int w = 0; w < WW; ++w) {
            const float x = xs[w][tid];
            sx += x; sxx += x * x;
        }
    }

    for (int t = 0; t < steps; ++t) {
        if (tid < FF) {
            const float m = sx * 0.1f;
            const float v = fmaxf(sxx * 0.1f - m * m, 0.f);
            stats[t & 1][tid] = make_float2(m, 1.0f / (sqrtf(v) + EPSC));
        }
        __syncthreads();   // one barrier per step; double-buffer makes it safe

        float* dst = out + (size_t)(b * NS + s0 + t) * NP;
        #pragma unroll
        for (int k = 0; k < NSLOT; ++k) {
            if (act[k]) {
                const float2 si = stats[t & 1][pi[k]];
                const float2 sj = stats[t & 1][pj[k]];
                dst[tid + k * 256] = (sxy[k] * 0.1f - si.x * sj.x) * si.y * sj.y;
            }
        }

        if (t + 1 < steps) {
            #pragma unroll
            for (int k = 0; k < NSLOT; ++k) {
                if (act[k]) {
                    const float xoi = xs[t][pi[k]],      xoj = xs[t][pj[k]];
                    const float xni = xs[t + WW][pi[k]], xnj = xs[t + WW][pj[k]];
                    sxy[k] += xni * xnj - xoi * xoj;
                }
            }
            if (tid < FF) {
                const float xo = xs[t][tid], xn = xs[t + WW][tid];
                sx  += xn - xo;
                sxx += xn * xn - xo * xo;
            }
        }
    }
}

extern "C" void kernel_launch(void* const* d_in, const int* in_sizes, int n_in,
                              void* d_out, int out_size, void* d_ws, size_t ws_size,
                              hipStream_t stream) {
    const float* in = (const float*)d_in[0];
    float* out = (float*)d_out;
    ts_corr_roll<<<BB * NCHUNK, 256, 0, stream>>>(in, out);
}

// Round 4
// 51.072 us; speedup vs baseline: 3.3882x; 1.9594x over previous
//
#include <hip/hip_runtime.h>

#define BB   128
#define TT   512
#define FF   40
#define WW   10
#define NS   503            // window starts (stride 1): T-W+1
#define NP   780            // F*(F-1)/2
#define SC   64             // steps per block (uniform; last chunk overlaps)
#define NCHUNK 8
#define ROWS (SC + WW - 1)  // 73 staged rows
#define NSLOT 4             // 256*4 = 1024 >= 780
#define EPSC 1e-5f

// One block per (b, 64-step s-chunk).
//  phase 0: stage xs[73][40] (contiguous slab, float4)
//  phase 1: stats table st[t][f] = (istd, m*istd) for ALL 64 steps  -> one barrier
//  phase 2: barrier-free rolling loop; per pair keep product history P[t%10]
//           in registers (static idx via unroll-by-10); per step per pair:
//           2 b32 xs reads + 2 b64 stats reads + 1 coalesced dword store.
__global__ __launch_bounds__(256, 4) void ts_corr_roll2(const float* __restrict__ in,
                                                        float* __restrict__ out) {
    const int blk = blockIdx.x;
    const int b   = blk / NCHUNK;
    const int c   = blk - b * NCHUNK;
    const int s0  = (c == NCHUNK - 1) ? (NS - SC) : c * SC;   // 439 for last (overlap ok)
    const int tid = threadIdx.x;

    __shared__ float  xs[ROWS][FF];     // 11680 B
    __shared__ float2 st[SC][FF];       // 20480 B  (istd, m*istd)

    // ---- phase 0: stage slab ----
    const float4* src4 = (const float4*)(in + ((size_t)b * TT + s0) * FF);
    float4* xs4 = (float4*)&xs[0][0];
    #pragma unroll
    for (int k = 0; k < 3; ++k) {
        const int i = tid + k * 256;
        if (i < ROWS * FF / 4) xs4[i] = src4[i];
    }
    __syncthreads();

    // ---- phase 1: stats for all steps (2560 cells = 10/thread) ----
    #pragma unroll
    for (int k = 0; k < 10; ++k) {
        const int cell = tid + k * 256;
        const int t = cell / FF;
        const int f = cell - t * FF;
        float sx = 0.f, sxx = 0.f;
        #pragma unroll
        for (int w = 0; w < WW; ++w) {
            const float x = xs[t + w][f];
            sx += x; sxx += x * x;
        }
        const float m = sx * 0.1f;
        const float v = fmaxf(sxx * 0.1f - m * m, 0.f);
        const float istd = 1.0f / (sqrtf(v) + EPSC);
        st[t][f] = make_float2(istd, m * istd);
    }

    // ---- pair setup + initial window (uses xs, ready since phase-0 barrier) ----
    int  pi[NSLOT], pj[NSLOT];
    bool act[NSLOT];
    float sxy[NSLOT], ph[NSLOT][WW];
    #pragma unroll
    for (int k = 0; k < NSLOT; ++k) {
        const int p = tid + k * 256;
        act[k] = (p < NP);
        const int pp = act[k] ? p : 0;
        int i = (int)((79.0f - sqrtf((float)(6241 - 8 * pp))) * 0.5f);
        while (i > 0 && i * (79 - i) / 2 > pp) --i;
        while ((i + 1) * (79 - (i + 1)) / 2 <= pp) ++i;
        pi[k] = i;
        pj[k] = pp - i * (79 - i) / 2 + i + 1;
        float s = 0.f;
        #pragma unroll
        for (int w = 0; w < WW; ++w) {
            const float pr = xs[w][pi[k]] * xs[w][pj[k]];
            ph[k][w] = pr;
            s += pr;
        }
        sxy[k] = s;
    }
    __syncthreads();   // stats table ready; no barriers after this

    // ---- phase 2: 64 steps, barrier-free ----
    float* dst0 = out + (size_t)(b * NS + s0) * NP;
    for (int t0 = 0; t0 < SC; t0 += WW) {
        #pragma unroll
        for (int u = 0; u < WW; ++u) {
            const int t = t0 + u;
            if (t >= SC) break;                  // only trips in the t0=60 block
            float* dst = dst0 + (size_t)t * NP;
            #pragma unroll
            for (int k = 0; k < NSLOT; ++k) {
                if (!act[k]) continue;
                const float2 si = st[t][pi[k]];
                const float2 sj = st[t][pj[k]];
                dst[tid + k * 256] = sxy[k] * 0.1f * si.x * sj.x - si.y * sj.y;
                if (t + 1 < SC) {
                    const float pn = xs[t + WW][pi[k]] * xs[t + WW][pj[k]];
                    sxy[k] += pn - ph[k][u];
                    ph[k][u] = pn;
                }
            }
        }
    }
}

extern "C" void kernel_launch(void* const* d_in, const int* in_sizes, int n_in,
                              void* d_out, int out_size, void* d_ws, size_t ws_size,
                              hipStream_t stream) {
    const float* in = (const float*)d_in[0];
    float* out = (float*)d_out;
    ts_corr_roll2<<<BB * NCHUNK, 256, 0, stream>>>(in, out);
}